// Round 7
// baseline (138.428 us; speedup 1.0000x reference)
//
#include <hip/hip_runtime.h>
#include <hip/hip_bf16.h>
#include <stdint.h>

// Problem constants: B=4, CIN=COUT=256, H=W=64, 3x3, pad=1, stride=1, dil=1
#define KDIM 2304   // CIN * 9, GEMM K

typedef __bf16 bf16_t;
typedef bf16_t bf16x8 __attribute__((ext_vector_type(8)));
typedef float f32x4 __attribute__((ext_vector_type(4)));
typedef float f32x2 __attribute__((ext_vector_type(2)));

__device__ __forceinline__ float b2f_lo(uint32_t u) {
  union { uint32_t i; float f; } c; c.i = u << 16; return c.f;
}
__device__ __forceinline__ float b2f_hi(uint32_t u) {
  union { uint32_t i; float f; } c; c.i = u & 0xffff0000u; return c.f;
}
__device__ __forceinline__ uint32_t pk_bf16(float a, float b) {
  __hip_bfloat162 h = __float22bfloat162_rn(make_float2(a, b));
  union { __hip_bfloat162 h; uint32_t u; } c; c.h = h; return c.u;
}

// async 16B global -> LDS; lds dst wave-uniform, HW adds lane*16
__device__ __forceinline__ void g2lds16(const uint16_t* g, uint16_t* l) {
  __builtin_amdgcn_global_load_lds((const __attribute__((address_space(1))) void*)g,
                                   (__attribute__((address_space(3))) void*)l,
                                   16, 0, 0);
}

// ---------------- merged prep kernel
// blocks [0,2048): x [4][256][64][64] f32 -> xt [4][64][64][256] bf16
// blocks [2048,2304): weight [256][256][3][3] f32 -> wt [cout][tap*256+cin] bf16
__global__ __launch_bounds__(256) void k_prep(const float* __restrict__ x,
                                              uint16_t* __restrict__ xt,
                                              const float* __restrict__ w,
                                              uint16_t* __restrict__ wt) {
  int tid = threadIdx.x;
  if (blockIdx.x < 2048) {
    __shared__ float tile[32][65];
    int b = blockIdx.x >> 9;
    int cgrp = (blockIdx.x >> 6) & 7;
    int sgrp = blockIdx.x & 63;
    int c0 = cgrp << 5, s0 = sgrp << 6;
#pragma unroll
    for (int it = 0; it < 2; ++it) {
      int f = tid + it * 256;
      int rr = f >> 4, col = (f & 15) << 2;
      float4 v = *(const float4*)&x[((size_t)(b * 256 + c0 + rr)) * 4096 + s0 + col];
      tile[rr][col + 0] = v.x;
      tile[rr][col + 1] = v.y;
      tile[rr][col + 2] = v.z;
      tile[rr][col + 3] = v.w;
    }
    __syncthreads();
    int sp = tid >> 2, cg = tid & 3;
    uint4 o;
    o.x = pk_bf16(tile[cg * 8 + 0][sp], tile[cg * 8 + 1][sp]);
    o.y = pk_bf16(tile[cg * 8 + 2][sp], tile[cg * 8 + 3][sp]);
    o.z = pk_bf16(tile[cg * 8 + 4][sp], tile[cg * 8 + 5][sp]);
    o.w = pk_bf16(tile[cg * 8 + 6][sp], tile[cg * 8 + 7][sp]);
    *(uint4*)&xt[((size_t)b * 4096 + s0 + sp) * 256 + c0 + cg * 8] = o;
  } else {
    __shared__ float wl[2304];
    int cout = blockIdx.x - 2048;
    const float* wrow = w + (size_t)cout * 2304;
    for (int i = tid; i < 576; i += 256)
      *(float4*)&wl[i * 4] = *(const float4*)&wrow[i * 4];
    __syncthreads();
    uint16_t* wdst = wt + (size_t)cout * KDIM + tid;
#pragma unroll
    for (int t = 0; t < 9; ++t)
      wdst[t * 256] = (uint16_t)(pk_bf16(wl[tid * 9 + t], 0.f) & 0xffffu);
  }
}

// per-thread bilinear corner setup for one tap (offsets read direct from global)
__device__ __forceinline__ void mk_corners(int tap, int wo, int ho, int b,
                                           const float* __restrict__ off,
                                           const float* __restrict__ msk,
                                           const uint16_t* xtb,
                                           float cw[4], const uint16_t* cp[4]) {
  int kh = tap / 3, kw = tap - kh * 3;
  size_t sp = (size_t)ho * 64 + wo;
  float dy = off[((size_t)(b * 18 + 2 * tap)) * 4096 + sp];
  float dx = off[((size_t)(b * 18 + 2 * tap + 1)) * 4096 + sp];
  float mm = msk[((size_t)(b * 9 + tap)) * 4096 + sp];
  float sy = (float)(ho - 1 + kh) + dy;
  float sx = (float)(wo - 1 + kw) + dx;
  float fy = floorf(sy), fx = floorf(sx);
  int y0 = (int)fy, x0 = (int)fx;
  float wy = sy - fy, wx = sx - fx;
#pragma unroll
  for (int cy = 0; cy < 2; ++cy) {
#pragma unroll
    for (int cx = 0; cx < 2; ++cx) {
      int y = y0 + cy, xx = x0 + cx;
      float wgt = (cy ? wy : 1.f - wy) * (cx ? wx : 1.f - wx) * mm;
      bool v = ((unsigned)y < 64u) && ((unsigned)xx < 64u);
      wgt = v ? wgt : 0.f;
      int yc = min(max(y, 0), 63), xc = min(max(xx, 0), 63);
      cw[cy * 2 + cx] = wgt;
      cp[cy * 2 + cx] = xtb + ((yc << 6) + xc) * 256;
    }
  }
}

// blend 4 corners (8 ch each) -> packed bf16x8
__device__ __forceinline__ uint4 blend4(const uint4 d[4], const float cw[4]) {
  f32x2 f0 = {0.f, 0.f}, f1 = {0.f, 0.f}, f2 = {0.f, 0.f}, f3 = {0.f, 0.f};
#pragma unroll
  for (int c = 0; c < 4; ++c) {
    f32x2 wc = {cw[c], cw[c]};
    f0 += wc * f32x2{b2f_lo(d[c].x), b2f_hi(d[c].x)};
    f1 += wc * f32x2{b2f_lo(d[c].y), b2f_hi(d[c].y)};
    f2 += wc * f32x2{b2f_lo(d[c].z), b2f_hi(d[c].z)};
    f3 += wc * f32x2{b2f_lo(d[c].w), b2f_hi(d[c].w)};
  }
  uint4 o;
  o.x = pk_bf16(f0.x, f0.y);
  o.y = pk_bf16(f1.x, f1.y);
  o.z = pk_bf16(f2.x, f2.y);
  o.w = pk_bf16(f3.x, f3.y);
  return o;
}

// ---------------- FUSED deform-im2col + GEMM, software-pipelined, 2 blocks/CU
// Block: 256 thr = 4 waves, BM=256 (all cout), BN=32 (half an output row), BK=64.
// Grid 512 = (b, ho, wo-half) -> 2 blocks/CU resident (LDS 72 KB each).
// 36 K-iters (9 taps x 4 quarters of 64 ch), double-buffered As/Bs, one barrier
// per iter; next-iter gathers + A-DMAs issued right after the barrier so they
// complete during the current iter's MFMA phase; second block covers the drain.
__global__ __launch_bounds__(256, 2) void k_fused(const uint16_t* __restrict__ xt,
                                                  const uint16_t* __restrict__ wt,
                                                  const float* __restrict__ off,
                                                  const float* __restrict__ msk,
                                                  const float* __restrict__ bias,
                                                  float* __restrict__ out) {
  __shared__ __align__(16) uint16_t As[2][2][256][32];  // 64 KB [buf][sub][m][kk]
  __shared__ __align__(16) uint16_t Bs[2][2][32][32];   //  8 KB [buf][sub][n][kk]

  int tid = threadIdx.x;
  int half = blockIdx.x & 1;
  int ho = (blockIdx.x >> 1) & 63;
  int b = blockIdx.x >> 7;
  int w0 = half << 5;

  int lane = tid & 63, wv = tid >> 6;
  int q = lane >> 4, r = lane & 15;

  // B gather mapping: position p (0..31), channel chunk cg*8 within 64-ch window
  int p = tid >> 3, cg = tid & 7;
  int wo_p = w0 + p;
  const uint16_t* xtb = xt + (size_t)b * 4096 * 256 + cg * 8;
  int bsub = cg >> 2, bcol = (cg & 3) * 8;

  // A DMA mapping: wave wv fills rows wv*64..wv*64+63 for both subs
  // DMA j covers rows wv*64 + j*16 .. +15; lane l -> row +(l>>2), ch (l&3)*8
  const uint16_t* abase = wt + (size_t)(wv * 64 + (lane >> 2)) * KDIM + (lane & 3) * 8;

  f32x4 acc[4][2];
#pragma unroll
  for (int i = 0; i < 4; ++i)
#pragma unroll
    for (int j = 0; j < 2; ++j) acc[i][j] = f32x4{0.f, 0.f, 0.f, 0.f};

  float cw[4];
  const uint16_t* cp[4];

  // ---- prologue: prepare iter 0 (tap 0, quarter 0) into buf 0
  mk_corners(0, wo_p, ho, b, off, msk, xtb, cw, cp);
  {
    uint4 d0[4];
#pragma unroll
    for (int c = 0; c < 4; ++c) d0[c] = *(const uint4*)(cp[c]);
#pragma unroll
    for (int s = 0; s < 2; ++s)
#pragma unroll
      for (int j = 0; j < 4; ++j)
        g2lds16(abase + s * 32 + (size_t)(j * 16) * KDIM, &As[0][s][wv * 64 + j * 16][0]);
    uint4 o = blend4(d0, cw);
    *(uint4*)&Bs[0][bsub][p][bcol] = o;
  }

  for (int i = 0; i < 36; ++i) {
    int cur = i & 1;
    __syncthreads();   // publish buf[cur] (drains A-DMA vmcnt + B ds_writes)
    uint4 dn[4];
    if (i != 35) {
      int nx = i + 1;
      if ((nx & 3) == 0) mk_corners(nx >> 2, wo_p, ho, b, off, msk, xtb, cw, cp);
      int ofs = (nx & 3) * 64;   // quarter offset within tap's 256 channels
#pragma unroll
      for (int c = 0; c < 4; ++c) dn[c] = *(const uint4*)(cp[c] + ofs);
      int ofsK = (nx >> 2) * 256 + (nx & 3) * 64;
      int nb = nx & 1;
#pragma unroll
      for (int s = 0; s < 2; ++s)
#pragma unroll
        for (int j = 0; j < 4; ++j)
          g2lds16(abase + ofsK + s * 32 + (size_t)(j * 16) * KDIM,
                  &As[nb][s][wv * 64 + j * 16][0]);
    }
    // ---- consume buf[cur]: 16 MFMA per wave
    bf16x8 af[4][2], bfr[2][2];
#pragma unroll
    for (int s = 0; s < 2; ++s) {
#pragma unroll
      for (int mi = 0; mi < 4; ++mi)
        af[mi][s] = *(const bf16x8*)&As[cur][s][wv * 64 + mi * 16 + r][q * 8];
#pragma unroll
      for (int ni = 0; ni < 2; ++ni)
        bfr[ni][s] = *(const bf16x8*)&Bs[cur][s][ni * 16 + r][q * 8];
    }
#pragma unroll
    for (int s = 0; s < 2; ++s)
#pragma unroll
      for (int mi = 0; mi < 4; ++mi)
#pragma unroll
        for (int ni = 0; ni < 2; ++ni)
          acc[mi][ni] = __builtin_amdgcn_mfma_f32_16x16x32_bf16(af[mi][s], bfr[ni][s], acc[mi][ni], 0, 0, 0);
    if (i != 35) {
      uint4 o = blend4(dn, cw);
      *(uint4*)&Bs[(i + 1) & 1][bsub][p][bcol] = o;
    }
  }

  // epilogue: C/D layout col = lane&15 (n), row = q*4 + j (m)
#pragma unroll
  for (int mi = 0; mi < 4; ++mi) {
#pragma unroll
    for (int j = 0; j < 4; ++j) {
      int m = wv * 64 + mi * 16 + q * 4 + j;
      float bv = bias[m];
#pragma unroll
      for (int ni = 0; ni < 2; ++ni) {
        int wo = w0 + ni * 16 + r;
        out[((size_t)(b * 256 + m)) * 4096 + ho * 64 + wo] = acc[mi][ni][j] + bv;
      }
    }
  }
}

extern "C" void kernel_launch(void* const* d_in, const int* in_sizes, int n_in,
                              void* d_out, int out_size, void* d_ws, size_t ws_size,
                              hipStream_t stream) {
  (void)in_sizes; (void)n_in; (void)out_size; (void)ws_size;
  const float* x      = (const float*)d_in[0];  // [4][256][64][64]
  const float* offset = (const float*)d_in[1];  // [4][18][64][64]
  const float* mask   = (const float*)d_in[2];  // [4][9][64][64]
  const float* weight = (const float*)d_in[3];  // [256][256][3][3]
  const float* bias   = (const float*)d_in[4];  // [256]
  float* out = (float*)d_out;                   // [4][256][64][64]

  uint8_t* ws = (uint8_t*)d_ws;
  uint16_t* xt = (uint16_t*)ws;                 // 8,388,608 B : NHWC bf16
  uint16_t* wt = (uint16_t*)(ws + 8388608);     // 1,179,648 B : [cout][tap*256+cin]

  k_prep<<<dim3(2304), 256, 0, stream>>>(x, xt, weight, wt);
  k_fused<<<dim3(512), 256, 0, stream>>>(xt, wt, offset, mask, bias, out);
}